// Round 2
// baseline (15456.441 us; speedup 1.0000x reference)
//
#include <hip/hip_runtime.h>

// Decoder ODE-RNN (GRU + Euler-2 ODE + softmax emit). Inputs/outputs FLOAT32.
// f32 GEMM emulated via bf16x3 splitting (6 MFMAs: hh+hm+mh+mm+hl+lh).
// R2 change vs 11.0ms R1:
//   - FUSED k_ode: tanh1/euler1/tanh2/euler2/emit/softmax in ONE kernel
//     (32 blocks x 16-row bands). h band lives in LDS f32; T tiles in LDS
//     bf16x3; W1/W2/We read per-lane DIRECT from global (L2-resident) as
//     MFMA fragments -> no LDS staging, no barriers inside GEMM k-loops.
//   - per step: 8 launches -> 3; five global intermediate roundtrips removed.
// h-trajectory numerics bit-identical to R1 (same splits, same MFMA order).

typedef __bf16 bf16_t;
typedef __bf16 bf16x8 __attribute__((ext_vector_type(8)));
typedef float  f32x4  __attribute__((ext_vector_type(4)));

#define BM 64
#define BN 64
#define BK 64
#define LDT 72     // gemm6 LDS row stride
#define LDT_T 136  // k_ode T tile stride (bf16)
#define LDT_H 1036 // k_ode h band stride (f32): 1036%32=12 -> ~2-way on frag reads
#define LDT_L 264  // k_ode logits stride (f32)

__device__ __forceinline__ float sigmoidf_(float x) { return 1.f / (1.f + expf(-x)); }

__device__ __forceinline__ void split3(float v, bf16_t& h, bf16_t& m, bf16_t& l) {
  h = (bf16_t)v; float r1 = v - (float)h;
  m = (bf16_t)r1; float r2 = r1 - (float)m;
  l = (bf16_t)r2;
}

#define CHAIN6(c, ah, am, al, bh, bm, bl) \
  c = __builtin_amdgcn_mfma_f32_16x16x32_bf16(ah, bh, c, 0, 0, 0); \
  c = __builtin_amdgcn_mfma_f32_16x16x32_bf16(ah, bm, c, 0, 0, 0); \
  c = __builtin_amdgcn_mfma_f32_16x16x32_bf16(am, bh, c, 0, 0, 0); \
  c = __builtin_amdgcn_mfma_f32_16x16x32_bf16(am, bm, c, 0, 0, 0); \
  c = __builtin_amdgcn_mfma_f32_16x16x32_bf16(ah, bl, c, 0, 0, 0); \
  c = __builtin_amdgcn_mfma_f32_16x16x32_bf16(al, bh, c, 0, 0, 0);

// flag-aware loads from HARNESS inputs (f32 vs bf16 decided at runtime)
__device__ __forceinline__ void loadf8(const void* p, size_t idx, int isf32, float out[8]) {
  if (isf32) {
    const float* q = (const float*)p + idx;
    f32x4 a = *(const f32x4*)q;
    f32x4 b = *(const f32x4*)(q + 4);
    out[0]=a[0]; out[1]=a[1]; out[2]=a[2]; out[3]=a[3];
    out[4]=b[0]; out[5]=b[1]; out[6]=b[2]; out[7]=b[3];
  } else {
    bf16x8 v = *(const bf16x8*)((const bf16_t*)p + idx);
#pragma unroll
    for (int i = 0; i < 8; i++) out[i] = (float)v[i];
  }
}
__device__ __forceinline__ float loadf(const void* p, int idx, int isf32) {
  return isf32 ? ((const float*)p)[idx] : (float)((const bf16_t*)p)[idx];
}

__global__ void k_probe(const unsigned int* ts_raw, int* flag) {
  *flag = (ts_raw[0] == 0u) ? 1 : 0;   // 1 = f32 inputs, 0 = bf16 inputs
}

// ---------------- split-precision GEMM core (used by gates/cand): C[64x64] tile.
template<bool CATX>
__device__ __forceinline__ void gemm6(
    const bf16_t* __restrict__ Ah, const bf16_t* __restrict__ Am, const bf16_t* __restrict__ Al,
    int lda,
    const void* __restrict__ X, int isf32, int t,
    const bf16_t* __restrict__ Bh, const bf16_t* __restrict__ Bm, const bf16_t* __restrict__ Bl,
    int K,
    f32x4 acc[2][2])
{
  __shared__ __align__(16) bf16_t As[3][BM * LDT];
  __shared__ __align__(16) bf16_t Bs[3][BN * LDT];

  const int tid  = threadIdx.x;
  const int srow = tid >> 2;
  const int sc   = (tid & 3) << 4;
  const int mBase = blockIdx.y * BM;
  const int nBase = blockIdx.x * BN;
  const int arow = mBase + srow;
  const int brow = nBase + srow;

  const int lane = tid & 63;
  const int wid  = tid >> 6;
  const int wm   = (wid & 1) * 32;
  const int wn   = (wid >> 1) * 32;
  const int q8   = (lane >> 4) << 3;
  const int l16  = lane & 15;

  f32x4 z = {0.f, 0.f, 0.f, 0.f};
#pragma unroll
  for (int i = 0; i < 2; i++)
#pragma unroll
    for (int j = 0; j < 2; j++) acc[i][j] = z;

  bf16x8 pA[3][2], pB[3][2];

  auto loadA = [&](int k0) {
    int gk = k0 + sc;
    if (CATX && gk >= 1024) {
      size_t off = (size_t)arow * 32768 + (size_t)t * 512 + (size_t)(gk - 1024);
      float v[16];
      loadf8(X, off,     isf32, v);
      loadf8(X, off + 8, isf32, v + 8);
#pragma unroll
      for (int u8 = 0; u8 < 2; u8++)
#pragma unroll
        for (int j = 0; j < 8; j++) {
          bf16_t h, m, l; split3(v[u8 * 8 + j], h, m, l);
          pA[0][u8][j] = h; pA[1][u8][j] = m; pA[2][u8][j] = l;
        }
    } else {
      size_t off = (size_t)arow * lda + gk;
      pA[0][0] = *(const bf16x8*)(Ah + off); pA[0][1] = *(const bf16x8*)(Ah + off + 8);
      pA[1][0] = *(const bf16x8*)(Am + off); pA[1][1] = *(const bf16x8*)(Am + off + 8);
      pA[2][0] = *(const bf16x8*)(Al + off); pA[2][1] = *(const bf16x8*)(Al + off + 8);
    }
  };
  auto loadB = [&](int k0) {
    size_t off = (size_t)brow * K + k0 + sc;
    pB[0][0] = *(const bf16x8*)(Bh + off); pB[0][1] = *(const bf16x8*)(Bh + off + 8);
    pB[1][0] = *(const bf16x8*)(Bm + off); pB[1][1] = *(const bf16x8*)(Bm + off + 8);
    pB[2][0] = *(const bf16x8*)(Bl + off); pB[2][1] = *(const bf16x8*)(Bl + off + 8);
  };

  loadA(0); loadB(0);

  for (int k0 = 0; k0 < K; k0 += BK) {
    const int wrow = srow * LDT + sc;
#pragma unroll
    for (int p = 0; p < 3; p++) {
      *(bf16x8*)&As[p][wrow]     = pA[p][0];
      *(bf16x8*)&As[p][wrow + 8] = pA[p][1];
      *(bf16x8*)&Bs[p][wrow]     = pB[p][0];
      *(bf16x8*)&Bs[p][wrow + 8] = pB[p][1];
    }
    __syncthreads();

    if (k0 + BK < K) { loadA(k0 + BK); loadB(k0 + BK); }

#pragma unroll
    for (int kk = 0; kk < BK; kk += 32) {
      bf16x8 a[2][3], b[2][3];
#pragma unroll
      for (int p = 0; p < 3; p++) {
        a[0][p] = *(const bf16x8*)&As[p][(wm +      l16) * LDT + kk + q8];
        a[1][p] = *(const bf16x8*)&As[p][(wm + 16 + l16) * LDT + kk + q8];
        b[0][p] = *(const bf16x8*)&Bs[p][(wn +      l16) * LDT + kk + q8];
        b[1][p] = *(const bf16x8*)&Bs[p][(wn + 16 + l16) * LDT + kk + q8];
      }
#pragma unroll
      for (int mi = 0; mi < 2; mi++)
#pragma unroll
        for (int ni = 0; ni < 2; ni++) {
          f32x4 c = acc[mi][ni];
          CHAIN6(c, a[mi][0], a[mi][1], a[mi][2], b[ni][0], b[ni][1], b[ni][2]);
          acc[mi][ni] = c;
        }
    }
    __syncthreads();
  }
}

#define EPI_COORDS \
  const int lane = threadIdx.x & 63; \
  const int wid  = threadIdx.x >> 6; \
  const int row0 = blockIdx.y * BM + (wid & 1) * 32 + ((lane >> 4) << 2); \
  const int col0 = blockIdx.x * BN + (wid >> 1) * 32 + (lane & 15);

// ---------------- gates: u = sigmoid([h,x]@Wu + bu) ; r likewise ; hr = h*r (bf16x3 out)
__global__ __launch_bounds__(256, 1) void k_gates(
    const bf16_t* __restrict__ hAh, const bf16_t* __restrict__ hAm, const bf16_t* __restrict__ hAl,
    const float* __restrict__ hAf,
    const void* __restrict__ data, int t,
    const bf16_t* __restrict__ Wh, const bf16_t* __restrict__ Wm, const bf16_t* __restrict__ Wl,
    const void* __restrict__ bu, const void* __restrict__ br,
    float* __restrict__ u_f32,
    bf16_t* __restrict__ hrh, bf16_t* __restrict__ hrm, bf16_t* __restrict__ hrl,
    const int* __restrict__ flg)
{
  const int isf32 = *flg;
  f32x4 acc[2][2];
  gemm6<true>(hAh, hAm, hAl, 1024, data, isf32, t, Wh, Wm, Wl, 1536, acc);
  EPI_COORDS
#pragma unroll
  for (int mi = 0; mi < 2; mi++)
#pragma unroll
    for (int ni = 0; ni < 2; ni++)
#pragma unroll
      for (int r = 0; r < 4; r++) {
        int m = row0 + mi * 16 + r;
        int n = col0 + ni * 16;
        float v = acc[mi][ni][r];
        if (n < 1024) {
          u_f32[m * 1024 + n] = sigmoidf_(v + loadf(bu, n, isf32));
        } else {
          int nn = n - 1024;
          float rr = sigmoidf_(v + loadf(br, nn, isf32));
          float hv = hAf[m * 1024 + nn] * rr;
          bf16_t h, mm_, l; split3(hv, h, mm_, l);
          int idx = m * 1024 + nn;
          hrh[idx] = h; hrm[idx] = mm_; hrl[idx] = l;
        }
      }
}

// ---------------- candidate + GRU blend: n = [hr,x]@Wn + bn ; h1 = (1-u)*n + u*h
__global__ __launch_bounds__(256, 1) void k_cand(
    const bf16_t* __restrict__ hrh, const bf16_t* __restrict__ hrm, const bf16_t* __restrict__ hrl,
    const void* __restrict__ data, int t,
    const bf16_t* __restrict__ Wh, const bf16_t* __restrict__ Wm, const bf16_t* __restrict__ Wl,
    const void* __restrict__ bn,
    const float* __restrict__ u_f32, const float* __restrict__ h_f32,
    float* __restrict__ h1f,
    bf16_t* __restrict__ h1h, bf16_t* __restrict__ h1m, bf16_t* __restrict__ h1l,
    const int* __restrict__ flg)
{
  const int isf32 = *flg;
  f32x4 acc[2][2];
  gemm6<true>(hrh, hrm, hrl, 1024, data, isf32, t, Wh, Wm, Wl, 1536, acc);
  EPI_COORDS
#pragma unroll
  for (int mi = 0; mi < 2; mi++)
#pragma unroll
    for (int ni = 0; ni < 2; ni++)
#pragma unroll
      for (int r = 0; r < 4; r++) {
        int m = row0 + mi * 16 + r;
        int n = col0 + ni * 16;
        int idx = m * 1024 + n;
        float nv = acc[mi][ni][r] + loadf(bn, n, isf32);
        float u = u_f32[idx];
        float h1 = (1.f - u) * nv + u * h_f32[idx];
        h1 = fminf(fmaxf(h1, -1e6f), 1e6f);   // insurance clamp
        h1f[idx] = h1;
        bf16_t h, mm_, l; split3(h1, h, mm_, l);
        h1h[idx] = h; h1m[idx] = mm_; h1l[idx] = l;
      }
}

// ---------------- FUSED ODE kernel: tanh1 -> euler1 -> tanh2 -> euler2 -> emit -> softmax
// grid = 32 blocks (16-row bands), 256 threads (4 waves).
// h band in LDS f32 (updated in place h1->h2->h3); T tiles in LDS bf16x3.
// W1T/W2T/WeT read per-lane direct from global (L2-resident), 1-deep prefetch.
__global__ __launch_bounds__(256, 1) void k_ode(
    const bf16_t* __restrict__ h1h, const bf16_t* __restrict__ h1m, const bf16_t* __restrict__ h1l,
    const float* __restrict__ h1f,
    const bf16_t* __restrict__ W1h, const bf16_t* __restrict__ W1m, const bf16_t* __restrict__ W1l,
    const bf16_t* __restrict__ W2h, const bf16_t* __restrict__ W2m, const bf16_t* __restrict__ W2l,
    const bf16_t* __restrict__ Weh, const bf16_t* __restrict__ Wem, const bf16_t* __restrict__ Wel,
    const void* __restrict__ b1, const void* __restrict__ b2, const void* __restrict__ be,
    const void* __restrict__ ts, int t,
    float* __restrict__ hOutf,
    bf16_t* __restrict__ hOuth, bf16_t* __restrict__ hOutm, bf16_t* __restrict__ hOutl,
    float* __restrict__ states, float* __restrict__ probs, const int* __restrict__ flg)
{
  __shared__ __align__(16) float  hS[16 * LDT_H];        // 66304 B
  __shared__ __align__(16) bf16_t TS[3][16 * LDT_T];     // 13056 B
  __shared__ __align__(16) float  lgS[16 * LDT_L];       // 16896 B

  const int tid  = threadIdx.x;
  const int lane = tid & 63;
  const int wid  = tid >> 6;
  const int l16  = lane & 15;
  const int q8   = (lane >> 4) << 3;
  const int r0   = blockIdx.x * 16;
  const int isf32 = *flg;
  const float sdt = 0.5f * (loadf(ts, t + 1, isf32) - loadf(ts, t, isf32));
  const f32x4 z4 = {0.f, 0.f, 0.f, 0.f};

  // ---- load h1 band into LDS f32 (coalesced)
#pragma unroll
  for (int i = 0; i < 16; i++) {
    int e = (tid + i * 256) * 4;          // element 0..16383
    int r = e >> 10, c = e & 1023;
    *(f32x4*)&hS[r * LDT_H + c] = *(const f32x4*)&h1f[(size_t)(r0 + r) * 1024 + c];
  }
  // (first barrier below covers this init before any cross-wave hS read)

  // ================== helpers ==================
  // tanh epilogue: acc -> bias -> tanh -> split3 -> TS
  auto tanh_epi = [&](const f32x4& a0, const f32x4& a1) {
#pragma unroll
    for (int f = 0; f < 2; f++)
#pragma unroll
      for (int r = 0; r < 4; r++) {
        int row = ((lane >> 4) << 2) + r;
        int col = (wid << 5) + (f << 4) + l16;
        float b = (col < 100) ? loadf(b1, col, isf32) : 0.f;
        float tv = tanhf(((f == 0) ? a0 : a1)[r] + b);
        bf16_t hh_, mm_, ll_; split3(tv, hh_, mm_, ll_);
        TS[0][row * LDT_T + col] = hh_;
        TS[1][row * LDT_T + col] = mm_;
        TS[2][row * LDT_T + col] = ll_;
      }
    __syncthreads();
  };

  // euler stage: accE = TS @ W2 ; h += sdt*(accE + b2) in LDS (in place)
  auto euler_stage = [&](int finalStage) {
    f32x4 accE[16];
#pragma unroll
    for (int i = 0; i < 16; i++) accE[i] = z4;
#pragma unroll
    for (int kk = 0; kk < 128; kk += 32) {
      bf16x8 a0 = *(const bf16x8*)&TS[0][l16 * LDT_T + kk + q8];
      bf16x8 a1 = *(const bf16x8*)&TS[1][l16 * LDT_T + kk + q8];
      bf16x8 a2 = *(const bf16x8*)&TS[2][l16 * LDT_T + kk + q8];
#pragma unroll
      for (int nf = 0; nf < 16; nf++) {
        size_t bo = (size_t)((wid << 8) + (nf << 4) + l16) * 128 + kk + q8;
        bf16x8 b0 = *(const bf16x8*)(W2h + bo);
        bf16x8 b1v = *(const bf16x8*)(W2m + bo);
        bf16x8 b2v = *(const bf16x8*)(W2l + bo);
        CHAIN6(accE[nf], a0, a1, a2, b0, b1v, b2v);
      }
    }
#pragma unroll
    for (int nf = 0; nf < 16; nf++)
#pragma unroll
      for (int r = 0; r < 4; r++) {
        int row = ((lane >> 4) << 2) + r;
        int col = (wid << 8) + (nf << 4) + l16;
        float hv = hS[row * LDT_H + col] + sdt * (accE[nf][r] + loadf(b2, col, isf32));
        hv = fminf(fmaxf(hv, -1e6f), 1e6f);   // insurance clamp
        hS[row * LDT_H + col] = hv;
        if (finalStage) {
          size_t gi = (size_t)(r0 + row) * 1024 + col;
          hOutf[gi] = hv;
          bf16_t hh_, mm_, ll_; split3(hv, hh_, mm_, ll_);
          hOuth[gi] = hh_; hOutm[gi] = mm_; hOutl[gi] = ll_;
          states[((size_t)t * 512 + r0 + row) * 1024 + col] = hv;
        }
      }
    __syncthreads();
  };

  // a-fragment from LDS h (f32) with in-register split
  auto ldA_hS = [&](bf16x8 aa[3], int k0) {
    const float* hp = &hS[l16 * LDT_H + k0 + q8];
    f32x4 u = *(const f32x4*)hp;
    f32x4 v = *(const f32x4*)(hp + 4);
    float vv[8] = {u[0], u[1], u[2], u[3], v[0], v[1], v[2], v[3]};
#pragma unroll
    for (int j = 0; j < 8; j++) {
      bf16_t h, m, l; split3(vv[j], h, m, l);
      aa[0][j] = h; aa[1][j] = m; aa[2][j] = l;
    }
  };

  // ================== stage A: tanh1 (A from global presplit h1) ==================
  {
    f32x4 acc0 = z4, acc1 = z4;
    bf16x8 a[3], c0[3], c1[3], na[3], nc0[3], nc1[3];
    auto ld = [&](bf16x8 aa[3], bf16x8 bb0[3], bf16x8 bb1[3], int k0) {
      size_t ao = (size_t)(r0 + l16) * 1024 + k0 + q8;
      aa[0] = *(const bf16x8*)(h1h + ao);
      aa[1] = *(const bf16x8*)(h1m + ao);
      aa[2] = *(const bf16x8*)(h1l + ao);
      size_t b0o = (size_t)((wid << 5) + l16) * 1024 + k0 + q8;
      size_t b1o = b0o + (size_t)16 * 1024;
      bb0[0] = *(const bf16x8*)(W1h + b0o); bb0[1] = *(const bf16x8*)(W1m + b0o); bb0[2] = *(const bf16x8*)(W1l + b0o);
      bb1[0] = *(const bf16x8*)(W1h + b1o); bb1[1] = *(const bf16x8*)(W1m + b1o); bb1[2] = *(const bf16x8*)(W1l + b1o);
    };
    ld(a, c0, c1, 0);
    for (int k0 = 0; k0 < 1024; k0 += 64) {
      ld(na, nc0, nc1, k0 + 32);
      CHAIN6(acc0, a[0], a[1], a[2], c0[0], c0[1], c0[2]);
      CHAIN6(acc1, a[0], a[1], a[2], c1[0], c1[1], c1[2]);
      if (k0 + 64 < 1024) ld(a, c0, c1, k0 + 64);
      CHAIN6(acc0, na[0], na[1], na[2], nc0[0], nc0[1], nc0[2]);
      CHAIN6(acc1, na[0], na[1], na[2], nc1[0], nc1[1], nc1[2]);
    }
    tanh_epi(acc0, acc1);
  }

  // ================== stage B: euler1 ==================
  euler_stage(0);

  // ================== stage C: tanh2 (A from LDS h2, split in-reg) ==================
  {
    f32x4 acc0 = z4, acc1 = z4;
    bf16x8 a[3], c0[3], c1[3], na[3], nc0[3], nc1[3];
    auto ldB = [&](bf16x8 bb0[3], bf16x8 bb1[3], int k0) {
      size_t b0o = (size_t)((wid << 5) + l16) * 1024 + k0 + q8;
      size_t b1o = b0o + (size_t)16 * 1024;
      bb0[0] = *(const bf16x8*)(W1h + b0o); bb0[1] = *(const bf16x8*)(W1m + b0o); bb0[2] = *(const bf16x8*)(W1l + b0o);
      bb1[0] = *(const bf16x8*)(W1h + b1o); bb1[1] = *(const bf16x8*)(W1m + b1o); bb1[2] = *(const bf16x8*)(W1l + b1o);
    };
    ldA_hS(a, 0); ldB(c0, c1, 0);
    for (int k0 = 0; k0 < 1024; k0 += 64) {
      ldA_hS(na, k0 + 32); ldB(nc0, nc1, k0 + 32);
      CHAIN6(acc0, a[0], a[1], a[2], c0[0], c0[1], c0[2]);
      CHAIN6(acc1, a[0], a[1], a[2], c1[0], c1[1], c1[2]);
      if (k0 + 64 < 1024) { ldA_hS(a, k0 + 64); ldB(c0, c1, k0 + 64); }
      CHAIN6(acc0, na[0], na[1], na[2], nc0[0], nc0[1], nc0[2]);
      CHAIN6(acc1, na[0], na[1], na[2], nc1[0], nc1[1], nc1[2]);
    }
    tanh_epi(acc0, acc1);
  }

  // ================== stage D: euler2 (writes h out + states) ==================
  euler_stage(1);

  // ================== stage E: emit (logits = h3 @ We + be) ==================
  {
    f32x4 accL[4];
#pragma unroll
    for (int i = 0; i < 4; i++) accL[i] = z4;
    bf16x8 a[3], bb[4][3], na[3], nbb[4][3];
    auto ldB = [&](bf16x8 b[4][3], int k0) {
#pragma unroll
      for (int nf = 0; nf < 4; nf++) {
        size_t bo = (size_t)((wid << 6) + (nf << 4) + l16) * 1024 + k0 + q8;
        b[nf][0] = *(const bf16x8*)(Weh + bo);
        b[nf][1] = *(const bf16x8*)(Wem + bo);
        b[nf][2] = *(const bf16x8*)(Wel + bo);
      }
    };
    ldA_hS(a, 0); ldB(bb, 0);
    for (int k0 = 0; k0 < 1024; k0 += 64) {
      ldA_hS(na, k0 + 32); ldB(nbb, k0 + 32);
#pragma unroll
      for (int nf = 0; nf < 4; nf++) { CHAIN6(accL[nf], a[0], a[1], a[2], bb[nf][0], bb[nf][1], bb[nf][2]); }
      if (k0 + 64 < 1024) { ldA_hS(a, k0 + 64); ldB(bb, k0 + 64); }
#pragma unroll
      for (int nf = 0; nf < 4; nf++) { CHAIN6(accL[nf], na[0], na[1], na[2], nbb[nf][0], nbb[nf][1], nbb[nf][2]); }
    }
#pragma unroll
    for (int nf = 0; nf < 4; nf++)
#pragma unroll
      for (int r = 0; r < 4; r++) {
        int row = ((lane >> 4) << 2) + r;
        int col = (wid << 6) + (nf << 4) + l16;
        lgS[row * LDT_L + col] = accL[nf][r] + loadf(be, col, isf32);
      }
    __syncthreads();
  }

  // ================== stage F: softmax over 256 cols per row ==================
  {
    int row = tid >> 4;         // 0..15
    int j   = tid & 15;
    float mx = -3.4e38f;
#pragma unroll
    for (int s = 0; s < 16; s++) mx = fmaxf(mx, lgS[row * LDT_L + j + 16 * s]);
    mx = fmaxf(mx, __shfl_xor(mx, 1));
    mx = fmaxf(mx, __shfl_xor(mx, 2));
    mx = fmaxf(mx, __shfl_xor(mx, 4));
    mx = fmaxf(mx, __shfl_xor(mx, 8));
    float e[16], sum = 0.f;
#pragma unroll
    for (int s = 0; s < 16; s++) { e[s] = expf(lgS[row * LDT_L + j + 16 * s] - mx); sum += e[s]; }
    sum += __shfl_xor(sum, 1);
    sum += __shfl_xor(sum, 2);
    sum += __shfl_xor(sum, 4);
    sum += __shfl_xor(sum, 8);
    float inv = 1.f / sum;
#pragma unroll
    for (int s = 0; s < 16; s++)
      probs[((size_t)t * 512 + r0 + row) * 256 + j + 16 * s] = e[s] * inv;
  }
}

// ---------------- weight transpose+split into bf16x3 [Npad][Kpad], zero-padded
__global__ void k_transpose_split(const void* __restrict__ src,
                                  bf16_t* __restrict__ dh, bf16_t* __restrict__ dm,
                                  bf16_t* __restrict__ dl,
                                  int K, int N, int Kpad, const int* __restrict__ flg)
{
  const int isf32 = *flg;
  int k = blockIdx.x * 256 + threadIdx.x;
  if (k >= Kpad) return;
  int n = blockIdx.y;  // < Npad
  float v = 0.f;
  if (k < K && n < N) v = loadf(src, k * N + n, isf32);
  bf16_t h, m, l; split3(v, h, m, l);
  size_t idx = (size_t)n * Kpad + k;
  dh[idx] = h; dm[idx] = m; dl[idx] = l;
}

extern "C" void kernel_launch(void* const* d_in, const int* in_sizes, int n_in,
                              void* d_out, int out_size, void* d_ws, size_t ws_size,
                              hipStream_t stream) {
  const void* data = d_in[0];
  const void* ts   = d_in[1];
  const void* Wu   = d_in[2];
  const void* bu   = d_in[3];
  const void* Wr   = d_in[4];
  const void* br   = d_in[5];
  const void* Wn   = d_in[6];
  const void* bn   = d_in[7];
  const void* W1   = d_in[8];
  const void* b1   = d_in[9];
  const void* W2   = d_in[10];
  const void* b2   = d_in[11];
  const void* We   = d_in[12];
  const void* be   = d_in[13];

  float* out_probs  = (float*)d_out;
  float* out_states = (float*)d_out + (size_t)63 * 512 * 256;

  char* p = (char*)d_ws;
  auto carve = [&](size_t bytes) { char* r = p; p += (bytes + 255) & ~255ull; return (void*)r; };
  int*    flg   = (int*)carve(256);
  // weights: bf16x3, transposed [Npad][Kpad]
  bf16_t* WurTh = (bf16_t*)carve((size_t)2048 * 1536 * 2);
  bf16_t* WurTm = (bf16_t*)carve((size_t)2048 * 1536 * 2);
  bf16_t* WurTl = (bf16_t*)carve((size_t)2048 * 1536 * 2);
  bf16_t* WnTh  = (bf16_t*)carve((size_t)1024 * 1536 * 2);
  bf16_t* WnTm  = (bf16_t*)carve((size_t)1024 * 1536 * 2);
  bf16_t* WnTl  = (bf16_t*)carve((size_t)1024 * 1536 * 2);
  bf16_t* W1Th  = (bf16_t*)carve((size_t)128 * 1024 * 2);
  bf16_t* W1Tm  = (bf16_t*)carve((size_t)128 * 1024 * 2);
  bf16_t* W1Tl  = (bf16_t*)carve((size_t)128 * 1024 * 2);
  bf16_t* W2Th  = (bf16_t*)carve((size_t)1024 * 128 * 2);
  bf16_t* W2Tm  = (bf16_t*)carve((size_t)1024 * 128 * 2);
  bf16_t* W2Tl  = (bf16_t*)carve((size_t)1024 * 128 * 2);
  bf16_t* WeTh  = (bf16_t*)carve((size_t)256 * 1024 * 2);
  bf16_t* WeTm  = (bf16_t*)carve((size_t)256 * 1024 * 2);
  bf16_t* WeTl  = (bf16_t*)carve((size_t)256 * 1024 * 2);
  // states: f32 + bf16x3
  float*  P0f = (float*)carve((size_t)512 * 1024 * 4);
  float*  P1f = (float*)carve((size_t)512 * 1024 * 4);
  bf16_t* P0h = (bf16_t*)carve((size_t)512 * 1024 * 2);
  bf16_t* P0m = (bf16_t*)carve((size_t)512 * 1024 * 2);
  bf16_t* P0l = (bf16_t*)carve((size_t)512 * 1024 * 2);
  bf16_t* P1h = (bf16_t*)carve((size_t)512 * 1024 * 2);
  bf16_t* P1m = (bf16_t*)carve((size_t)512 * 1024 * 2);
  bf16_t* P1l = (bf16_t*)carve((size_t)512 * 1024 * 2);
  bf16_t* HRh = (bf16_t*)carve((size_t)512 * 1024 * 2);
  bf16_t* HRm = (bf16_t*)carve((size_t)512 * 1024 * 2);
  bf16_t* HRl = (bf16_t*)carve((size_t)512 * 1024 * 2);
  float*  uf  = (float*)carve((size_t)512 * 1024 * 4);

  // h0 = 0 (f32 and bf16x3 views)
  (void)hipMemsetAsync(P0f, 0, (size_t)512 * 1024 * 4, stream);
  (void)hipMemsetAsync(P0h, 0, (size_t)512 * 1024 * 2, stream);
  (void)hipMemsetAsync(P0m, 0, (size_t)512 * 1024 * 2, stream);
  (void)hipMemsetAsync(P0l, 0, (size_t)512 * 1024 * 2, stream);

  dim3 b256(256);
  k_probe<<<1, 1, 0, stream>>>((const unsigned int*)ts, flg);

  k_transpose_split<<<dim3(6, 1024), b256, 0, stream>>>(Wu, WurTh, WurTm, WurTl, 1536, 1024, 1536, flg);
  k_transpose_split<<<dim3(6, 1024), b256, 0, stream>>>(Wr, WurTh + (size_t)1024 * 1536,
                                                        WurTm + (size_t)1024 * 1536,
                                                        WurTl + (size_t)1024 * 1536, 1536, 1024, 1536, flg);
  k_transpose_split<<<dim3(6, 1024), b256, 0, stream>>>(Wn, WnTh, WnTm, WnTl, 1536, 1024, 1536, flg);
  k_transpose_split<<<dim3(4, 128),  b256, 0, stream>>>(W1, W1Th, W1Tm, W1Tl, 1024, 100, 1024, flg);
  k_transpose_split<<<dim3(1, 1024), b256, 0, stream>>>(W2, W2Th, W2Tm, W2Tl, 100, 1024, 128, flg);
  k_transpose_split<<<dim3(4, 256),  b256, 0, stream>>>(We, WeTh, WeTm, WeTl, 1024, 256, 1024, flg);

  for (int t = 0; t < 63; t++) {
    // chain: P0 (h) -> gates/cand -> P1 -> fused ODE/emit/softmax -> P0 (next h)
    k_gates<<<dim3(32, 8), b256, 0, stream>>>(P0h, P0m, P0l, P0f, data, t,
                                              WurTh, WurTm, WurTl, bu, br,
                                              uf, HRh, HRm, HRl, flg);
    k_cand <<<dim3(16, 8), b256, 0, stream>>>(HRh, HRm, HRl, data, t,
                                              WnTh, WnTm, WnTl, bn, uf, P0f,
                                              P1f, P1h, P1m, P1l, flg);
    k_ode  <<<32, b256, 0, stream>>>(P1h, P1m, P1l, P1f,
                                     W1Th, W1Tm, W1Tl,
                                     W2Th, W2Tm, W2Tl,
                                     WeTh, WeTm, WeTl,
                                     b1, b2, be, ts, t,
                                     P0f, P0h, P0m, P0l,
                                     out_states, out_probs, flg);
  }
}